// Round 11
// baseline (497.196 us; speedup 1.0000x reference)
//
#include <hip/hip_runtime.h>
#include <hip/hip_bf16.h>

typedef __bf16 bf16;
typedef __bf16 bf16x4 __attribute__((ext_vector_type(4)));
typedef __bf16 bf16x8 __attribute__((ext_vector_type(8)));
typedef float f32x4 __attribute__((ext_vector_type(4)));

#define NB   32768
#define EMB  768
#define MSUB 32
#define KC   256
#define DSUB 24

// ws layout (bytes):
//   [0,     512K )  cb_pad: bf16 [32][256][32]  (d padded 24->32 with zeros)
//   [1M,  2.125M)  rot_bf: bf16 [768][768]
//   [4M,    54M )  xrb   : bf16 [32768][768]    (natural layout)

__device__ __forceinline__ bf16x8 cvt8(float4 a, float4 b) {
    bf16x8 r;
    r[0] = (bf16)a.x; r[1] = (bf16)a.y; r[2] = (bf16)a.z; r[3] = (bf16)a.w;
    r[4] = (bf16)b.x; r[5] = (bf16)b.y; r[6] = (bf16)b.z; r[7] = (bf16)b.w;
    return r;
}

// LDS-only barrier: waits LDS ops (lgkmcnt) but NOT global stores (vmcnt),
// so the store queue stays full across phases.
__device__ __forceinline__ void lds_barrier() {
    asm volatile("s_waitcnt lgkmcnt(0)" ::: "memory");
    __builtin_amdgcn_s_barrier();
    __builtin_amdgcn_sched_barrier(0);
}

// ---------------------------------------------------------------- kernel 0
__global__ __launch_bounds__(256, 4)
void pq_prep(const float* __restrict__ cb, const float* __restrict__ rot,
             bf16* __restrict__ cb_pad, bf16* __restrict__ rot_bf) {
    const int b = blockIdx.x;
    const int t = threadIdx.x;
    if (b < 288) {                       // rot: 768*768 = 288*2048
        const int o = b * 2048 + t * 8;
        float4 a0 = *(const float4*)(rot + o);
        float4 a1 = *(const float4*)(rot + o + 4);
        *(bf16x8*)(rot_bf + o) = cvt8(a0, a1);
    } else {                             // cb pad+cvt: [m][k][24] -> bf16 [m][k][32]
        const int o  = (b - 288) * 2048 + t * 8;   // 32*256*32 = 128*2048
        const int m  = o >> 13;
        const int k  = (o >> 5) & 255;
        const int d0 = o & 31;           // 0,8,16,24
        bf16x8 v;
        if (d0 < DSUB) {
            const float* cp = cb + (size_t)(m * KC + k) * DSUB + d0;
            v = cvt8(*(const float4*)cp, *(const float4*)(cp + 4));
        } else {
            const float4 fz = {0.f, 0.f, 0.f, 0.f};
            v = cvt8(fz, fz);
        }
        *(bf16x8*)(cb_pad + o) = v;
    }
}

// ---------------------------------------------------------------- kernel 1
// xr = x @ rot^T via swapped MFMA: D[j][row] = mfma(A=rot_frag, B=x_frag).
// Acc regs hold 4 CONSECUTIVE j per lane -> direct bf16x4 stores.
__global__ __launch_bounds__(512, 3)
void pq_rot(const float* __restrict__ x, const bf16* __restrict__ rot_bf,
            bf16* __restrict__ xrb) {
    __shared__ bf16 g_lds[96 * 32 * 8];   // x bf16 granules [e8][row][slot], 48 KiB

    const int tid  = threadIdx.x;
    const int w    = tid >> 6;
    const int lane = tid & 63;
    const int l15  = lane & 15;
    const int lg   = lane >> 4;
    const int rowbase = blockIdx.x * 32;

    #pragma unroll
    for (int i = 0; i < 6; ++i) {
        const int oct = i * 512 + tid;
        const int row = oct & 31;
        const int e8  = oct >> 5;
        const float* xp = x + (size_t)(rowbase + row) * EMB + e8 * 8;
        *(bf16x8*)&g_lds[(e8 * 32 + row) * 8] =
            cvt8(*(const float4*)xp, *(const float4*)(xp + 4));
    }
    __syncthreads();

    f32x4 acc[2][6];
    #pragma unroll
    for (int rt = 0; rt < 2; ++rt)
        #pragma unroll
        for (int jt = 0; jt < 6; ++jt)
            acc[rt][jt] = (f32x4){0.f, 0.f, 0.f, 0.f};

    const int jbase = w * 96;
    #pragma unroll 2
    for (int e0 = 0; e0 < EMB; e0 += 32) {
        bf16x8 xfrag[2];
        #pragma unroll
        for (int rt = 0; rt < 2; ++rt)
            xfrag[rt] = *(const bf16x8*)&g_lds[(((e0 >> 3) + lg) * 32 + rt * 16 + l15) * 8];
        #pragma unroll
        for (int jt = 0; jt < 6; ++jt) {
            const bf16* bp = rot_bf + (size_t)(jbase + jt * 16 + l15) * EMB + e0 + lg * 8;
            bf16x8 rotfrag = *(const bf16x8*)bp;
            acc[0][jt] = __builtin_amdgcn_mfma_f32_16x16x32_bf16(rotfrag, xfrag[0], acc[0][jt], 0, 0, 0);
            acc[1][jt] = __builtin_amdgcn_mfma_f32_16x16x32_bf16(rotfrag, xfrag[1], acc[1][jt], 0, 0, 0);
        }
    }

    #pragma unroll
    for (int rt = 0; rt < 2; ++rt) {
        #pragma unroll
        for (int jt = 0; jt < 6; ++jt) {
            bf16x4 v;
            #pragma unroll
            for (int r = 0; r < 4; ++r) v[r] = (bf16)acc[rt][jt][r];
            bf16* p = xrb + (size_t)(rowbase + rt * 16 + l15) * EMB
                          + jbase + jt * 16 + lg * 4;
            *(bf16x4*)p = v;
        }
    }
}

// ---------------------------------------------------------------- kernel 2
// scores via MFMA with ALL HBM reads hoisted to a prologue burst:
// xall[8] (16 VGPR) holds every xs fragment this wave will ever need, so
// the 8 phases touch only cb_pad (L2-resident) + LDS + global STORES ->
// the kernel's HBM profile is fillBuffer-shaped (one read burst, then a
// pure write stream; no read/write turnaround sprinkle).
#define STG_ROW 1044
__global__ __launch_bounds__(256, 2)
void pq_scores8(const bf16* __restrict__ xrb, const bf16* __restrict__ cb_pad,
                float* __restrict__ out) {
    __shared__ float stg[16 * STG_ROW];   // 66,816 B -> 2 blocks/CU

    const int tid  = threadIdx.x;
    const int lane = tid & 63;
    const int w    = tid >> 6;          // 0..3
    const int l15  = lane & 15;
    const int hi   = lane >> 4;         // 0..3

    // XCD-bijective swizzle: 2048 blocks, 256 contiguous rowtiles per XCD
    const int bid = (int)blockIdx.x;
    const int swz = (bid & 7) * 256 + (bid >> 3);
    const int rowbase = swz * 16;

    // prologue: hoist all xs fragments (phase mm uses m = mm*4+w).
    // (m==31,hi==3 reads d=24..31 past the row: finite garbage x cb_pad
    // zeros = 0; stays within the 4.3 GB workspace.)
    const bf16* xrow = xrb + (size_t)(rowbase + l15) * EMB + hi * 8;
    bf16x8 xall[8];
    #pragma unroll
    for (int mm = 0; mm < 8; ++mm)
        xall[mm] = *(const bf16x8*)(xrow + (mm * 4 + w) * DSUB);

    #pragma unroll 1
    for (int mm = 0; mm < 8; ++mm) {
        const int m = mm * 4 + w;

        // 16 k-tiles: A-frag = cb_pad[m][kt*16+l15][hi*8 ..+7]  (L2-resident)
        const bf16* cbm = cb_pad + (size_t)m * (KC * 32);
        f32x4 acc[16];
        #pragma unroll
        for (int kt = 0; kt < 16; ++kt) {
            bf16x8 cfrag = *(const bf16x8*)(cbm + (kt * 16 + l15) * 32 + hi * 8);
            acc[kt] = __builtin_amdgcn_mfma_f32_16x16x32_bf16(
                cfrag, xall[mm], (f32x4){0.f, 0.f, 0.f, 0.f}, 0, 0, 0);
        }

        // stage: lane l, reg r -> D[kc = kt*16+hi*4+r][docrow = l15]
        #pragma unroll
        for (int kt = 0; kt < 16; ++kt)
            *(f32x4*)&stg[l15 * STG_ROW + w * 260 + kt * 16 + hi * 4] = acc[kt];

        lds_barrier();   // stage visible; does NOT drain global stores

        // drain: wave w -> rows w*4..+3; per row 4 consecutive m = 4 KB contig
        #pragma unroll
        for (int j = 0; j < 4; ++j) {
            const int row = w * 4 + j;
            float* op = out + ((size_t)(rowbase + row) * MSUB + mm * 4) * KC + 4 * lane;
            #pragma unroll
            for (int ms = 0; ms < 4; ++ms) {
                f32x4 v = *(const f32x4*)&stg[row * STG_ROW + ms * 260 + 4 * lane];
                *(f32x4*)(op + ms * KC) = v;
            }
        }

        lds_barrier();   // drain reads done before next stage overwrites
    }
}

extern "C" void kernel_launch(void* const* d_in, const int* in_sizes, int n_in,
                              void* d_out, int out_size, void* d_ws, size_t ws_size,
                              hipStream_t stream) {
    const float* x   = (const float*)d_in[0];   // [32768, 768]
    const float* cbk = (const float*)d_in[1];   // [32, 256, 24]
    const float* rot = (const float*)d_in[2];   // [768, 768]
    float* out = (float*)d_out;                 // [32768, 32, 256]

    char* ws = (char*)d_ws;
    bf16* cb_pad = (bf16*)(ws);
    bf16* rot_bf = (bf16*)(ws + (1u << 20));
    bf16* xrb    = (bf16*)(ws + (4u << 20));

    hipLaunchKernelGGL(pq_prep,     dim3(416),  dim3(256), 0, stream, cbk, rot, cb_pad, rot_bf);
    hipLaunchKernelGGL(pq_rot,      dim3(1024), dim3(512), 0, stream, x, rot_bf, xrb);
    hipLaunchKernelGGL(pq_scores8,  dim3(2048), dim3(256), 0, stream, xrb, cb_pad, out);
}

// Round 12
// 430.796 us; speedup vs baseline: 1.1541x; 1.1541x over previous
//
#include <hip/hip_runtime.h>
#include <hip/hip_bf16.h>

typedef __bf16 bf16;
typedef __bf16 bf16x4 __attribute__((ext_vector_type(4)));
typedef __bf16 bf16x8 __attribute__((ext_vector_type(8)));
typedef float f32x4 __attribute__((ext_vector_type(4)));

#define NB   32768
#define EMB  768
#define MSUB 32
#define KC   256
#define DSUB 24

// ws layout (bytes):
//   [0,     512K )  cb_pad: bf16 [32][256][32]  (d padded 24->32 with zeros)
//   [1M,  2.125M)  rot_bf: bf16 [768][768]
//   [4M,    54M )  xr2   : bf16 [tile(2048)][m(32)][r(16)][d(24)]
//                  scores-native: one wave-phase = one ~784B contiguous read

__device__ __forceinline__ bf16x8 cvt8(float4 a, float4 b) {
    bf16x8 r;
    r[0] = (bf16)a.x; r[1] = (bf16)a.y; r[2] = (bf16)a.z; r[3] = (bf16)a.w;
    r[4] = (bf16)b.x; r[5] = (bf16)b.y; r[6] = (bf16)b.z; r[7] = (bf16)b.w;
    return r;
}

// LDS-only barrier: waits LDS ops (lgkmcnt) but NOT global stores (vmcnt),
// so the store queue stays full across phases.
__device__ __forceinline__ void lds_barrier() {
    asm volatile("s_waitcnt lgkmcnt(0)" ::: "memory");
    __builtin_amdgcn_s_barrier();
    __builtin_amdgcn_sched_barrier(0);
}

// ---------------------------------------------------------------- kernel 0
__global__ __launch_bounds__(256, 4)
void pq_prep(const float* __restrict__ cb, const float* __restrict__ rot,
             bf16* __restrict__ cb_pad, bf16* __restrict__ rot_bf) {
    const int b = blockIdx.x;
    const int t = threadIdx.x;
    if (b < 288) {                       // rot: 768*768 = 288*2048
        const int o = b * 2048 + t * 8;
        float4 a0 = *(const float4*)(rot + o);
        float4 a1 = *(const float4*)(rot + o + 4);
        *(bf16x8*)(rot_bf + o) = cvt8(a0, a1);
    } else {                             // cb pad+cvt: [m][k][24] -> bf16 [m][k][32]
        const int o  = (b - 288) * 2048 + t * 8;   // 32*256*32 = 128*2048
        const int m  = o >> 13;
        const int k  = (o >> 5) & 255;
        const int d0 = o & 31;           // 0,8,16,24
        bf16x8 v;
        if (d0 < DSUB) {
            const float* cp = cb + (size_t)(m * KC + k) * DSUB + d0;
            v = cvt8(*(const float4*)cp, *(const float4*)(cp + 4));
        } else {
            const float4 fz = {0.f, 0.f, 0.f, 0.f};
            v = cvt8(fz, fz);
        }
        *(bf16x8*)(cb_pad + o) = v;
    }
}

// ---------------------------------------------------------------- kernel 1
// xr = x @ rot^T via swapped MFMA: D[j][row] = mfma(A=rot_frag, B=x_frag).
// Epilogue stores into the scores-native xr2 layout:
//   xr2[((row>>4)*32 + j/24)*16 + (row&15)]*24 + j%24
// Each lane's 4-consecutive-j chunk is 4-aligned and 24%4==0, so the chunk
// never crosses an m boundary -> single bf16x4 store per (rt,jt).
__global__ __launch_bounds__(512, 3)
void pq_rot(const float* __restrict__ x, const bf16* __restrict__ rot_bf,
            bf16* __restrict__ xr2) {
    __shared__ bf16 g_lds[96 * 32 * 8];   // x bf16 granules [e8][row][slot], 48 KiB

    const int tid  = threadIdx.x;
    const int w    = tid >> 6;
    const int lane = tid & 63;
    const int l15  = lane & 15;
    const int lg   = lane >> 4;
    const int rowbase = blockIdx.x * 32;

    #pragma unroll
    for (int i = 0; i < 6; ++i) {
        const int oct = i * 512 + tid;
        const int row = oct & 31;
        const int e8  = oct >> 5;
        const float* xp = x + (size_t)(rowbase + row) * EMB + e8 * 8;
        *(bf16x8*)&g_lds[(e8 * 32 + row) * 8] =
            cvt8(*(const float4*)xp, *(const float4*)(xp + 4));
    }
    __syncthreads();

    f32x4 acc[2][6];
    #pragma unroll
    for (int rt = 0; rt < 2; ++rt)
        #pragma unroll
        for (int jt = 0; jt < 6; ++jt)
            acc[rt][jt] = (f32x4){0.f, 0.f, 0.f, 0.f};

    const int jbase = w * 96;
    #pragma unroll 2
    for (int e0 = 0; e0 < EMB; e0 += 32) {
        bf16x8 xfrag[2];
        #pragma unroll
        for (int rt = 0; rt < 2; ++rt)
            xfrag[rt] = *(const bf16x8*)&g_lds[(((e0 >> 3) + lg) * 32 + rt * 16 + l15) * 8];
        #pragma unroll
        for (int jt = 0; jt < 6; ++jt) {
            const bf16* bp = rot_bf + (size_t)(jbase + jt * 16 + l15) * EMB + e0 + lg * 8;
            bf16x8 rotfrag = *(const bf16x8*)bp;
            acc[0][jt] = __builtin_amdgcn_mfma_f32_16x16x32_bf16(rotfrag, xfrag[0], acc[0][jt], 0, 0, 0);
            acc[1][jt] = __builtin_amdgcn_mfma_f32_16x16x32_bf16(rotfrag, xfrag[1], acc[1][jt], 0, 0, 0);
        }
    }

    // epilogue: lane holds xr[row = rowbase+rt*16+l15][j0..j0+3],
    // j0 = jbase + jt*16 + lg*4 -> (m = j0/24, d0 = j0%24), store bf16x4
    #pragma unroll
    for (int rt = 0; rt < 2; ++rt) {
        #pragma unroll
        for (int jt = 0; jt < 6; ++jt) {
            const int j0 = jbase + jt * 16 + lg * 4;
            const int m  = j0 / DSUB;
            const int d0 = j0 % DSUB;
            bf16x4 v;
            #pragma unroll
            for (int r = 0; r < 4; ++r) v[r] = (bf16)acc[rt][jt][r];
            bf16* p = xr2 + ((size_t)((blockIdx.x * 2 + rt) * MSUB + m) * 16 + l15) * DSUB + d0;
            *(bf16x4*)p = v;
        }
    }
}

// ---------------------------------------------------------------- kernel 2
// scores via MFMA, R10 body, xr2 contiguous-read layout. Per wave-phase the
// xs read is ONE ~784B contiguous region (7 full 128B lines) instead of 16
// scattered 64B segments at 1536B stride.
#define STG_ROW 1044
__global__ __launch_bounds__(256, 2)
void pq_scores9(const bf16* __restrict__ xr2, const bf16* __restrict__ cb_pad,
                float* __restrict__ out) {
    __shared__ float stg[16 * STG_ROW];   // 66,816 B -> 2 blocks/CU

    const int tid  = threadIdx.x;
    const int lane = tid & 63;
    const int w    = tid >> 6;          // 0..3
    const int l15  = lane & 15;
    const int hi   = lane >> 4;         // 0..3

    // XCD-bijective swizzle: 2048 blocks, 256 contiguous rowtiles per XCD
    const int bid = (int)blockIdx.x;
    const int swz = (bid & 7) * 256 + (bid >> 3);
    const int rowbase = swz * 16;

    #pragma unroll 1
    for (int mm = 0; mm < 8; ++mm) {
        const int m = mm * 4 + w;

        // xs B-frag: xr2[(swz*32+m)*16 + l15][hi*8 ..+7]; hi==3 reads d=24..31
        // = next row's d0..7 (finite garbage x cb_pad zeros = 0; last access
        // lands 16B past xr2, still deep inside the 4.3GB workspace).
        const bf16* xp = xr2 + ((size_t)(swz * MSUB + m) * 16 + l15) * DSUB + hi * 8;
        bf16x8 xfrag = *(const bf16x8*)xp;

        // 16 k-tiles: A-frag = cb_pad[m][kt*16+l15][hi*8 ..+7]  (L2-resident)
        const bf16* cbm = cb_pad + (size_t)m * (KC * 32);
        f32x4 acc[16];
        #pragma unroll
        for (int kt = 0; kt < 16; ++kt) {
            bf16x8 cfrag = *(const bf16x8*)(cbm + (kt * 16 + l15) * 32 + hi * 8);
            acc[kt] = __builtin_amdgcn_mfma_f32_16x16x32_bf16(
                cfrag, xfrag, (f32x4){0.f, 0.f, 0.f, 0.f}, 0, 0, 0);
        }

        // stage: lane l, reg r -> D[kc = kt*16+hi*4+r][docrow = l15]
        #pragma unroll
        for (int kt = 0; kt < 16; ++kt)
            *(f32x4*)&stg[l15 * STG_ROW + w * 260 + kt * 16 + hi * 4] = acc[kt];

        lds_barrier();   // stage visible; does NOT drain global stores

        // drain: wave w -> rows w*4..+3; per row 4 consecutive m = 4 KB contig
        #pragma unroll
        for (int j = 0; j < 4; ++j) {
            const int row = w * 4 + j;
            float* op = out + ((size_t)(rowbase + row) * MSUB + mm * 4) * KC + 4 * lane;
            #pragma unroll
            for (int ms = 0; ms < 4; ++ms) {
                f32x4 v = *(const f32x4*)&stg[row * STG_ROW + ms * 260 + 4 * lane];
                *(f32x4*)(op + ms * KC) = v;
            }
        }

        lds_barrier();   // drain reads done before next stage overwrites
    }
}

extern "C" void kernel_launch(void* const* d_in, const int* in_sizes, int n_in,
                              void* d_out, int out_size, void* d_ws, size_t ws_size,
                              hipStream_t stream) {
    const float* x   = (const float*)d_in[0];   // [32768, 768]
    const float* cbk = (const float*)d_in[1];   // [32, 256, 24]
    const float* rot = (const float*)d_in[2];   // [768, 768]
    float* out = (float*)d_out;                 // [32768, 32, 256]

    char* ws = (char*)d_ws;
    bf16* cb_pad = (bf16*)(ws);
    bf16* rot_bf = (bf16*)(ws + (1u << 20));
    bf16* xr2    = (bf16*)(ws + (4u << 20));

    hipLaunchKernelGGL(pq_prep,     dim3(416),  dim3(256), 0, stream, cbk, rot, cb_pad, rot_bf);
    hipLaunchKernelGGL(pq_rot,      dim3(1024), dim3(512), 0, stream, x, rot_bf, xr2);
    hipLaunchKernelGGL(pq_scores9,  dim3(2048), dim3(256), 0, stream, xr2, cb_pad, out);
}